// Round 2
// baseline (372.057 us; speedup 1.0000x reference)
//
#include <hip/hip_runtime.h>

#define N_VOX 120000
#define C64 64
#define K27 27
#define KC 13          // center offset index (0,0,0): nbr[n][13] == n always
#define NOFF 26
#define CAP 4096       // pair capacity per k (expected ~1100, 28σ headroom)
#define VPW 8          // voxels per wave in the dense center GEMM
#define BLKS_PER_K 16  // correction kernel: blocks per offset k

// ---------------- ws layout ----------------
// @0        int   cnt[26*64]      (padded: one counter per 256B line)
// @8192     float bnp[256]        (s1, sh1, s2, sh2)
// @16384    int2  pairs[26*CAP]   (n_out, m_in)  ~852KB
// @1MB      float bufA[N*64]      layer-1 pre-activation / mid  ~30.7MB
#define WS_CNT_OFF   0
#define WS_BNP_OFF   8192
#define WS_PAIR_OFF  16384
#define WS_BUFA_OFF  (1u << 20)

// ---- prep: fold BN into scale/shift, zero pair counters ----
__global__ void prep_kernel(const float* __restrict__ g1, const float* __restrict__ b1,
                            const float* __restrict__ m1, const float* __restrict__ v1,
                            const float* __restrict__ g2, const float* __restrict__ b2,
                            const float* __restrict__ m2, const float* __restrict__ v2,
                            float* __restrict__ bnp, int* __restrict__ cnt) {
    int i = threadIdx.x;  // 256 threads
    if (i < C64) {
        float s1 = g1[i] * rsqrtf(v1[i] + 1e-5f);
        bnp[0 * C64 + i] = s1;
        bnp[1 * C64 + i] = b1[i] - m1[i] * s1;
        float s2 = g2[i] * rsqrtf(v2[i] + 1e-5f);
        bnp[2 * C64 + i] = s2;
        bnp[3 * C64 + i] = b2[i] - m2[i] * s2;
    }
    if (i < NOFF) cnt[i * 64] = 0;
}

// ---- compaction: per-k lists of (n, m) for off-center active neighbors ----
__global__ __launch_bounds__(256) void compact_kernel(const int* __restrict__ nbr,
                                                      int* __restrict__ cnt,
                                                      int2* __restrict__ pairs) {
    int n = blockIdx.x * blockDim.x + threadIdx.x;
    if (n >= N_VOX) return;
    const int* row = nbr + (size_t)n * K27;
#pragma unroll
    for (int k = 0; k < K27; ++k) {
        if (k == KC) continue;
        int m = row[k];
        if (m >= 0) {
            int kk = (k < KC) ? k : k - 1;  // 0..25
            int slot = atomicAdd(&cnt[kk * 64], 1);
            if (slot < CAP) pairs[kk * CAP + slot] = make_int2(n, m);
        }
    }
}

// ---- dense center GEMM: pre[n,d] = sum_c f[n,c] * W13[c,d] ----
__global__ __launch_bounds__(256) void center_gemm_kernel(const float* __restrict__ fin,
                                                          const float* __restrict__ W13,  // [64,64]
                                                          float* __restrict__ pre) {
    const int lane = threadIdx.x & 63;
    int wid = blockIdx.x * (blockDim.x >> 6) + (threadIdx.x >> 6);
    const int n0 = wid * VPW;
    if (n0 >= N_VOX) return;

    // W13 column for this lane: 64 VGPRs, reused across 8 voxels
    float w[C64];
#pragma unroll
    for (int c = 0; c < C64; ++c) w[c] = W13[c * C64 + lane];

    float acc[VPW];
#pragma unroll
    for (int v = 0; v < VPW; ++v) acc[v] = 0.f;

    const float4* fr[VPW];
#pragma unroll
    for (int v = 0; v < VPW; ++v) fr[v] = (const float4*)(fin + (size_t)(n0 + v) * C64);

    // c-outer / v-inner: 8 independent FMA chains for ILP
#pragma unroll
    for (int c4 = 0; c4 < C64 / 4; ++c4) {
        float4 fq[VPW];
#pragma unroll
        for (int v = 0; v < VPW; ++v) fq[v] = fr[v][c4];
#pragma unroll
        for (int v = 0; v < VPW; ++v) {
            acc[v] = fmaf(fq[v].x, w[c4 * 4 + 0], acc[v]);
            acc[v] = fmaf(fq[v].y, w[c4 * 4 + 1], acc[v]);
            acc[v] = fmaf(fq[v].z, w[c4 * 4 + 2], acc[v]);
            acc[v] = fmaf(fq[v].w, w[c4 * 4 + 3], acc[v]);
        }
    }

#pragma unroll
    for (int v = 0; v < VPW; ++v) pre[(size_t)(n0 + v) * C64 + lane] = acc[v];
}

// ---- corrections: for each pair (n,m) of offset k: pre[n,:] += f[m,:] @ W[k] ----
__global__ __launch_bounds__(256) void correction_kernel(const float* __restrict__ fin,
                                                         const float* __restrict__ W,  // [27,64,64]
                                                         const int* __restrict__ cnt,
                                                         const int2* __restrict__ pairs,
                                                         float* __restrict__ pre) {
    const int lane = threadIdx.x & 63;
    const int kk = blockIdx.x / BLKS_PER_K;                                  // 0..25
    const int ww = (blockIdx.x % BLKS_PER_K) * 4 + (threadIdx.x >> 6);       // 0..63
    const int k = (kk < KC) ? kk : kk + 1;                                   // real offset
    const int count = cnt[kk * 64];
    if (count == 0) return;

    // W[k] column for this lane (64 VGPRs), amortized over all pairs of this wave
    float w[C64];
    const float* Wk = W + (size_t)k * C64 * C64 + lane;
#pragma unroll
    for (int c = 0; c < C64; ++c) w[c] = Wk[c * C64];

    const int2* pk = pairs + (size_t)kk * CAP;
    const int WPK = BLKS_PER_K * 4;  // waves per k

    for (int base = ww * 4; base < count; base += WPK * 4) {
        float a[4] = {0.f, 0.f, 0.f, 0.f};
        int nn[4];
        const float4* fr[4];
#pragma unroll
        for (int j = 0; j < 4; ++j) {
            bool valid = (base + j) < count;
            int2 p = valid ? pk[base + j] : make_int2(-1, 0);
            nn[j] = p.x;
            fr[j] = (const float4*)(fin + (size_t)p.y * C64);
        }
#pragma unroll
        for (int c4 = 0; c4 < C64 / 4; ++c4) {
            float4 fq[4];
#pragma unroll
            for (int j = 0; j < 4; ++j) fq[j] = fr[j][c4];
#pragma unroll
            for (int j = 0; j < 4; ++j) {
                a[j] = fmaf(fq[j].x, w[c4 * 4 + 0], a[j]);
                a[j] = fmaf(fq[j].y, w[c4 * 4 + 1], a[j]);
                a[j] = fmaf(fq[j].z, w[c4 * 4 + 2], a[j]);
                a[j] = fmaf(fq[j].w, w[c4 * 4 + 3], a[j]);
            }
        }
#pragma unroll
        for (int j = 0; j < 4; ++j) {
            if (nn[j] >= 0) atomicAdd(&pre[(size_t)nn[j] * C64 + lane], a[j]);
        }
    }
}

// ---- BN + ReLU (+ residual), in-place capable, float4 ----
template <bool RES>
__global__ __launch_bounds__(256) void bn_relu_kernel(const float* __restrict__ pre,
                                                      float* __restrict__ outp,
                                                      const float* __restrict__ bnp,  // sc[64], sh[64]
                                                      const float* __restrict__ res) {
    const int total4 = N_VOX * C64 / 4;
    const float4* sc4 = (const float4*)bnp;
    const float4* sh4 = (const float4*)(bnp + C64);
    for (int i = blockIdx.x * blockDim.x + threadIdx.x; i < total4; i += gridDim.x * blockDim.x) {
        int c4 = i & 15;  // channel quad
        float4 s = sc4[c4], h = sh4[c4];
        float4 x = ((const float4*)pre)[i];
        float4 o;
        o.x = fmaf(x.x, s.x, h.x);
        o.y = fmaf(x.y, s.y, h.y);
        o.z = fmaf(x.z, s.z, h.z);
        o.w = fmaf(x.w, s.w, h.w);
        if (RES) {
            float4 r = ((const float4*)res)[i];
            o.x += r.x; o.y += r.y; o.z += r.z; o.w += r.w;
        }
        o.x = fmaxf(o.x, 0.f);
        o.y = fmaxf(o.y, 0.f);
        o.z = fmaxf(o.z, 0.f);
        o.w = fmaxf(o.w, 0.f);
        ((float4*)outp)[i] = o;
    }
}

extern "C" void kernel_launch(void* const* d_in, const int* in_sizes, int n_in,
                              void* d_out, int out_size, void* d_ws, size_t ws_size,
                              hipStream_t stream) {
    const float* f   = (const float*)d_in[0];
    const float* W1  = (const float*)d_in[1];
    const float* g1  = (const float*)d_in[2];
    const float* b1  = (const float*)d_in[3];
    const float* m1  = (const float*)d_in[4];
    const float* v1  = (const float*)d_in[5];
    const float* W2  = (const float*)d_in[6];
    const float* g2  = (const float*)d_in[7];
    const float* b2  = (const float*)d_in[8];
    const float* m2  = (const float*)d_in[9];
    const float* v2  = (const float*)d_in[10];
    const int*   nbr = (const int*)d_in[11];
    float* out = (float*)d_out;

    char* ws = (char*)d_ws;
    int*   cnt   = (int*)(ws + WS_CNT_OFF);
    float* bnp   = (float*)(ws + WS_BNP_OFF);
    int2*  pairs = (int2*)(ws + WS_PAIR_OFF);
    float* bufA  = (float*)(ws + WS_BUFA_OFF);

    prep_kernel<<<1, 256, 0, stream>>>(g1, b1, m1, v1, g2, b2, m2, v2, bnp, cnt);
    compact_kernel<<<(N_VOX + 255) / 256, 256, 0, stream>>>(nbr, cnt, pairs);

    const int gemm_blocks = (N_VOX / VPW + 3) / 4;  // 3750
    const int corr_blocks = NOFF * BLKS_PER_K;      // 416
    const int ew_blocks   = 2048;

    // ---- layer 1: pre in bufA, BN+ReLU in place (bufA becomes mid) ----
    center_gemm_kernel<<<gemm_blocks, 256, 0, stream>>>(f, W1 + KC * C64 * C64, bufA);
    correction_kernel<<<corr_blocks, 256, 0, stream>>>(f, W1, cnt, pairs, bufA);
    bn_relu_kernel<false><<<ew_blocks, 256, 0, stream>>>(bufA, bufA, bnp, nullptr);

    // ---- layer 2: pre in d_out, BN+ReLU+residual in place ----
    center_gemm_kernel<<<gemm_blocks, 256, 0, stream>>>(bufA, W2 + KC * C64 * C64, out);
    correction_kernel<<<corr_blocks, 256, 0, stream>>>(bufA, W2, cnt, pairs, out);
    bn_relu_kernel<true><<<ew_blocks, 256, 0, stream>>>(out, out, bnp + 2 * C64, f);
}

// Round 4
// 207.713 us; speedup vs baseline: 1.7912x; 1.7912x over previous
//
#include <hip/hip_runtime.h>

typedef short short8 __attribute__((ext_vector_type(8)));
typedef float f32x4 __attribute__((ext_vector_type(4)));

#define N_VOX 120000
#define C64 64
#define K27 27
#define KC 13
#define NOFF 26
#define CAP 4096
#define CORR_BPK 18   // blocks per offset k
#define LAYER_STRIDE 110592  // 27 * 4096 bf16 elems per layer in packed W

// ---- ws layout ----
#define WS_CNT   0           // 26*64 int
#define WS_BNP   8192        // 256 floats: s1,h1,s2,h2
#define WS_PACKW 16384       // 2*27*4096 bf16 = 442368 B
#define WS_PAIRS 524288      // 26*CAP*8 = 832 KB
#define WS_FBF   (2u << 20)  // N*64 bf16 = 14.65 MB
#define WS_MIDBF (18u << 20) // N*64 bf16

__device__ __forceinline__ ushort f2bf(float x) {  // fp32 -> bf16 RNE
    uint u = __float_as_uint(x);
    u = (u + 0x7FFFu + ((u >> 16) & 1u)) >> 16;
    return (ushort)u;
}

// ---- prep: fold BN, zero counters ----
__global__ void prep_kernel(const float* g1, const float* b1, const float* m1, const float* v1,
                            const float* g2, const float* b2, const float* m2, const float* v2,
                            float* bnp, int* cnt) {
    int i = threadIdx.x;  // 256
    if (i < C64) {
        float s1 = g1[i] * rsqrtf(v1[i] + 1e-5f);
        bnp[i] = s1; bnp[64 + i] = b1[i] - m1[i] * s1;
        float s2 = g2[i] * rsqrtf(v2[i] + 1e-5f);
        bnp[128 + i] = s2; bnp[192 + i] = b2[i] - m2[i] * s2;
    }
    if (i < NOFF) cnt[i * 64] = 0;
}

// ---- pack W1,W2 (bf16) into b-fragment order ----
// pw[L*110592 + k*4096 + ks*2048 + t*512 + lane*8 + j] = W[L][k][c][d]
//   c = ks*32 + (lane>>4)*8 + j,  d = t*16 + (lane&15)
__global__ __launch_bounds__(256) void packw_kernel(const float* __restrict__ W1,
                                                    const float* __restrict__ W2,
                                                    ushort* __restrict__ pw) {
    int idx = blockIdx.x * 256 + threadIdx.x;  // 221184 total
    int j = idx & 7, lane = (idx >> 3) & 63, t = (idx >> 9) & 3, ks = (idx >> 11) & 1;
    int kL = idx >> 12; int k = kL % K27; int L = kL / K27;
    if (L >= 2) return;
    int c = ks * 32 + (lane >> 4) * 8 + j;
    int d = t * 16 + (lane & 15);
    const float* W = L ? W2 : W1;
    pw[idx] = f2bf(W[(size_t)k * 4096 + c * 64 + d]);
}

// ---- fp32 features -> bf16 ----
__global__ __launch_bounds__(256) void fcvt_kernel(const float* __restrict__ f,
                                                   ushort* __restrict__ fb) {
    const int total = N_VOX * C64 / 8;
    for (int i = blockIdx.x * 256 + threadIdx.x; i < total; i += gridDim.x * 256) {
        float4 x0 = ((const float4*)f)[i * 2];
        float4 x1 = ((const float4*)f)[i * 2 + 1];
        short8 o;
        o[0] = f2bf(x0.x); o[1] = f2bf(x0.y); o[2] = f2bf(x0.z); o[3] = f2bf(x0.w);
        o[4] = f2bf(x1.x); o[5] = f2bf(x1.y); o[6] = f2bf(x1.z); o[7] = f2bf(x1.w);
        ((short8*)fb)[i] = o;
    }
}

// ---- compaction: per-k pair lists ----
__global__ __launch_bounds__(256) void compact_kernel(const int* __restrict__ nbr,
                                                      int* __restrict__ cnt,
                                                      int2* __restrict__ pairs) {
    int n = blockIdx.x * blockDim.x + threadIdx.x;
    if (n >= N_VOX) return;
    const int* row = nbr + (size_t)n * K27;
#pragma unroll
    for (int k = 0; k < K27; ++k) {
        if (k == KC) continue;
        int m = row[k];
        if (m >= 0) {
            int kk = (k < KC) ? k : k - 1;
            int slot = atomicAdd(&cnt[kk * 64], 1);
            if (slot < CAP) pairs[kk * CAP + slot] = make_int2(n, m);
        }
    }
}

// ---- dense center GEMM via MFMA ----
__global__ __launch_bounds__(256) void center_mfma_kernel(const ushort* __restrict__ fb,
                                                          const ushort* __restrict__ pwc,  // k=13 slice
                                                          float* __restrict__ pre) {
    const int lane = threadIdx.x & 63;
    const int r16 = lane & 15, kg = lane >> 4;
    const int wid = blockIdx.x * 4 + (threadIdx.x >> 6);
    const int n0 = wid * 32;
    if (n0 >= N_VOX) return;

    const short8* B = (const short8*)pwc;
    short8 Bf[2][4];
#pragma unroll
    for (int s = 0; s < 2; ++s)
#pragma unroll
        for (int t = 0; t < 4; ++t) Bf[s][t] = B[(s * 4 + t) * 64 + lane];

    f32x4 acc[2][4];
#pragma unroll
    for (int v = 0; v < 2; ++v)
#pragma unroll
        for (int t = 0; t < 4; ++t) acc[v][t] = (f32x4)0.f;

#pragma unroll
    for (int v = 0; v < 2; ++v) {
        const short8* arow = (const short8*)(fb + (size_t)(n0 + v * 16 + r16) * C64);
        short8 a0 = arow[kg];      // k = kg*8 + j
        short8 a1 = arow[4 + kg];  // k = 32 + kg*8 + j
#pragma unroll
        for (int t = 0; t < 4; ++t) {
            acc[v][t] = __builtin_amdgcn_mfma_f32_16x16x32_bf16(a0, Bf[0][t], acc[v][t], 0, 0, 0);
            acc[v][t] = __builtin_amdgcn_mfma_f32_16x16x32_bf16(a1, Bf[1][t], acc[v][t], 0, 0, 0);
        }
    }

#pragma unroll
    for (int v = 0; v < 2; ++v)
#pragma unroll
        for (int t = 0; t < 4; ++t)
#pragma unroll
            for (int r = 0; r < 4; ++r)
                pre[(size_t)(n0 + v * 16 + kg * 4 + r) * C64 + t * 16 + r16] = acc[v][t][r];
}

// ---- corrections via gather-MFMA + atomic scatter ----
__global__ __launch_bounds__(256) void corr_mfma_kernel(const ushort* __restrict__ fb,
                                                        const ushort* __restrict__ pwl,  // layer base
                                                        const int* __restrict__ cnt,
                                                        const int2* __restrict__ pairs,
                                                        float* __restrict__ pre) {
    const int lane = threadIdx.x & 63;
    const int r16 = lane & 15, kg = lane >> 4;
    const int kk = blockIdx.x / CORR_BPK;
    const int wv = (blockIdx.x % CORR_BPK) * 4 + (threadIdx.x >> 6);
    const int k = (kk < KC) ? kk : kk + 1;
    int count = cnt[kk * 64];
    if (count > CAP) count = CAP;
    if (count == 0) return;

    const short8* B = (const short8*)(pwl + (size_t)k * 4096);
    short8 Bf[2][4];
#pragma unroll
    for (int s = 0; s < 2; ++s)
#pragma unroll
        for (int t = 0; t < 4; ++t) Bf[s][t] = B[(s * 4 + t) * 64 + lane];

    const int2* pk = pairs + (size_t)kk * CAP;
    const int groups = (count + 15) >> 4;

    for (int g = wv; g < groups; g += CORR_BPK * 4) {
        const int base = g * 16;
        int m = -1;
        if (base + r16 < count) m = pk[base + r16].y;
        short8 a0 = (short8)0, a1 = (short8)0;
        if (m >= 0) {
            const short8* arow = (const short8*)(fb + (size_t)m * C64);
            a0 = arow[kg];
            a1 = arow[4 + kg];
        }
        f32x4 acc[4];
#pragma unroll
        for (int t = 0; t < 4; ++t) acc[t] = (f32x4)0.f;
#pragma unroll
        for (int t = 0; t < 4; ++t) {
            acc[t] = __builtin_amdgcn_mfma_f32_16x16x32_bf16(a0, Bf[0][t], acc[t], 0, 0, 0);
            acc[t] = __builtin_amdgcn_mfma_f32_16x16x32_bf16(a1, Bf[1][t], acc[t], 0, 0, 0);
        }
#pragma unroll
        for (int r = 0; r < 4; ++r) {
            const int idx = base + kg * 4 + r;
            if (idx < count) {
                const int n = pk[idx].x;
                float* dst = pre + (size_t)n * C64 + r16;
#pragma unroll
                for (int t = 0; t < 4; ++t) unsafeAtomicAdd(dst + t * 16, acc[t][r]);
            }
        }
    }
}

// ---- BN+ReLU -> bf16 mid ----
__global__ __launch_bounds__(256) void bnrelu1_kernel(const float* __restrict__ pre,
                                                      const float* __restrict__ bnp,
                                                      ushort* __restrict__ midb) {
    const int total = N_VOX * C64 / 8;
    for (int i = blockIdx.x * 256 + threadIdx.x; i < total; i += gridDim.x * 256) {
        const int c0 = (i & 7) * 8;
        float4 s0 = *(const float4*)(bnp + c0);
        float4 s1 = *(const float4*)(bnp + c0 + 4);
        float4 h0 = *(const float4*)(bnp + 64 + c0);
        float4 h1 = *(const float4*)(bnp + 64 + c0 + 4);
        float4 x0 = ((const float4*)pre)[i * 2];
        float4 x1 = ((const float4*)pre)[i * 2 + 1];
        short8 o;
        o[0] = f2bf(fmaxf(fmaf(x0.x, s0.x, h0.x), 0.f));
        o[1] = f2bf(fmaxf(fmaf(x0.y, s0.y, h0.y), 0.f));
        o[2] = f2bf(fmaxf(fmaf(x0.z, s0.z, h0.z), 0.f));
        o[3] = f2bf(fmaxf(fmaf(x0.w, s0.w, h0.w), 0.f));
        o[4] = f2bf(fmaxf(fmaf(x1.x, s1.x, h1.x), 0.f));
        o[5] = f2bf(fmaxf(fmaf(x1.y, s1.y, h1.y), 0.f));
        o[6] = f2bf(fmaxf(fmaf(x1.z, s1.z, h1.z), 0.f));
        o[7] = f2bf(fmaxf(fmaf(x1.w, s1.w, h1.w), 0.f));
        ((short8*)midb)[i] = o;
    }
}

// ---- BN + residual + ReLU, fp32 in-place ----
__global__ __launch_bounds__(256) void bnrelu2_kernel(float* __restrict__ pre,
                                                      const float* __restrict__ bnp2,
                                                      const float* __restrict__ res) {
    const int total = N_VOX * C64 / 8;
    for (int i = blockIdx.x * 256 + threadIdx.x; i < total; i += gridDim.x * 256) {
        const int c0 = (i & 7) * 8;
        float4 s0 = *(const float4*)(bnp2 + c0);
        float4 s1 = *(const float4*)(bnp2 + c0 + 4);
        float4 h0 = *(const float4*)(bnp2 + 64 + c0);
        float4 h1 = *(const float4*)(bnp2 + 64 + c0 + 4);
        float4 x0 = ((float4*)pre)[i * 2];
        float4 x1 = ((float4*)pre)[i * 2 + 1];
        float4 r0 = ((const float4*)res)[i * 2];
        float4 r1 = ((const float4*)res)[i * 2 + 1];
        float4 o0, o1;
        o0.x = fmaxf(fmaf(x0.x, s0.x, h0.x) + r0.x, 0.f);
        o0.y = fmaxf(fmaf(x0.y, s0.y, h0.y) + r0.y, 0.f);
        o0.z = fmaxf(fmaf(x0.z, s0.z, h0.z) + r0.z, 0.f);
        o0.w = fmaxf(fmaf(x0.w, s0.w, h0.w) + r0.w, 0.f);
        o1.x = fmaxf(fmaf(x1.x, s1.x, h1.x) + r1.x, 0.f);
        o1.y = fmaxf(fmaf(x1.y, s1.y, h1.y) + r1.y, 0.f);
        o1.z = fmaxf(fmaf(x1.z, s1.z, h1.z) + r1.z, 0.f);
        o1.w = fmaxf(fmaf(x1.w, s1.w, h1.w) + r1.w, 0.f);
        ((float4*)pre)[i * 2] = o0;
        ((float4*)pre)[i * 2 + 1] = o1;
    }
}

extern "C" void kernel_launch(void* const* d_in, const int* in_sizes, int n_in,
                              void* d_out, int out_size, void* d_ws, size_t ws_size,
                              hipStream_t stream) {
    const float* f   = (const float*)d_in[0];
    const float* W1  = (const float*)d_in[1];
    const float* g1  = (const float*)d_in[2];
    const float* b1  = (const float*)d_in[3];
    const float* m1  = (const float*)d_in[4];
    const float* v1  = (const float*)d_in[5];
    const float* W2  = (const float*)d_in[6];
    const float* g2  = (const float*)d_in[7];
    const float* b2  = (const float*)d_in[8];
    const float* m2  = (const float*)d_in[9];
    const float* v2  = (const float*)d_in[10];
    const int*   nbr = (const int*)d_in[11];
    float* out = (float*)d_out;

    char* ws = (char*)d_ws;
    int*    cnt   = (int*)(ws + WS_CNT);
    float*  bnp   = (float*)(ws + WS_BNP);
    ushort* pw    = (ushort*)(ws + WS_PACKW);
    int2*   pairs = (int2*)(ws + WS_PAIRS);
    ushort* fbf   = (ushort*)(ws + WS_FBF);
    ushort* midb  = (ushort*)(ws + WS_MIDBF);

    prep_kernel<<<1, 256, 0, stream>>>(g1, b1, m1, v1, g2, b2, m2, v2, bnp, cnt);
    packw_kernel<<<864, 256, 0, stream>>>(W1, W2, pw);
    fcvt_kernel<<<1024, 256, 0, stream>>>(f, fbf);
    compact_kernel<<<(N_VOX + 255) / 256, 256, 0, stream>>>(nbr, cnt, pairs);

    const int gemm_blocks = (N_VOX / 32 + 3) / 4;  // 938
    const int corr_blocks = NOFF * CORR_BPK;       // 468
    const int ew_blocks   = 2048;

    // layer 1: pre in d_out, then BN+ReLU -> bf16 mid
    center_mfma_kernel<<<gemm_blocks, 256, 0, stream>>>(fbf, pw + KC * 4096, out);
    corr_mfma_kernel<<<corr_blocks, 256, 0, stream>>>(fbf, pw, cnt, pairs, out);
    bnrelu1_kernel<<<ew_blocks, 256, 0, stream>>>(out, bnp, midb);

    // layer 2: pre in d_out (fully overwritten), then BN+resid+ReLU in place
    center_mfma_kernel<<<gemm_blocks, 256, 0, stream>>>(midb, pw + LAYER_STRIDE + KC * 4096, out);
    corr_mfma_kernel<<<corr_blocks, 256, 0, stream>>>(midb, pw + LAYER_STRIDE, cnt, pairs, out);
    bnrelu2_kernel<<<ew_blocks, 256, 0, stream>>>(out, bnp + 128, f);
}

// Round 5
// 183.463 us; speedup vs baseline: 2.0280x; 1.1322x over previous
//
#include <hip/hip_runtime.h>

typedef short short8 __attribute__((ext_vector_type(8)));
typedef float f32x4 __attribute__((ext_vector_type(4)));

#define N_VOX 120000
#define C64 64
#define K27 27
#define KC 13
#define TILES 3750          // N_VOX / 32
#define CAPT 64             // CSR entries per tile (mean 7.8, 20-sigma headroom)
#define LAYER_W 110592      // 27*4096 bf16 elems per layer (VALU-packed W)

// ---- ws layout ----
#define WS_TCNT 0                 // TILES int               (15 KB)
#define WS_BNP  16384             // 256 floats: s1,h1,s2,h2
#define WS_PWC  20480             // 2*4096 bf16  center frag-packed W (k=KC)
#define WS_PWV  40960             // 2*110592 bf16 VALU-packed W (all k)
#define WS_ENTS 524288            // TILES*CAPT int2         (1.92 MB)
#define WS_MIDB (4u << 20)        // N*64 bf16               (15.36 MB)

__device__ __forceinline__ ushort f2bf(float x) {  // fp32 -> bf16 RNE
    uint u = __float_as_uint(x);
    u = (u + 0x7FFFu + ((u >> 16) & 1u)) >> 16;
    return (ushort)u;
}
__device__ __forceinline__ float bf2f(ushort u) {
    return __uint_as_float((uint)u << 16);
}

// ---- prep: pack W (two layouts), zero tile counters, fold BN ----
// flat tid ranges:
//   [0, 221184)            : pwv[i] = bf16(W[L][i % 110592]) (same layout, bf16)
//   [221184, 229376)       : pwc frag-pack of W[L][KC]
//   [229376, 233126)       : tcnt zero
//   [233126, 233190)       : BN fold
__global__ __launch_bounds__(256) void prep_kernel(const float* __restrict__ W1,
                                                   const float* __restrict__ W2,
                                                   const float* g1, const float* b1,
                                                   const float* m1, const float* v1,
                                                   const float* g2, const float* b2,
                                                   const float* m2, const float* v2,
                                                   ushort* __restrict__ pwv,
                                                   ushort* __restrict__ pwc,
                                                   int* __restrict__ tcnt,
                                                   float* __restrict__ bnp) {
    int tid = blockIdx.x * 256 + threadIdx.x;
    if (tid < 221184) {
        int L = tid / LAYER_W, r = tid % LAYER_W;
        const float* W = L ? W2 : W1;
        pwv[tid] = f2bf(W[r]);
    } else if (tid < 229376) {
        int j2 = tid - 221184;
        int L = j2 >> 12, q = j2 & 4095;
        int ks = q >> 11, tq = (q >> 9) & 3, ln = (q >> 3) & 63, jj = q & 7;
        int c = ks * 32 + (ln >> 4) * 8 + jj;
        int d = tq * 16 + (ln & 15);
        const float* W = L ? W2 : W1;
        pwc[L * 4096 + q] = f2bf(W[(size_t)KC * 4096 + c * 64 + d]);
    } else if (tid < 233126) {
        tcnt[tid - 229376] = 0;
    } else if (tid < 233190) {
        int i = tid - 233126;
        float s1 = g1[i] * rsqrtf(v1[i] + 1e-5f);
        bnp[i] = s1; bnp[64 + i] = b1[i] - m1[i] * s1;
        float s2 = g2[i] * rsqrtf(v2[i] + 1e-5f);
        bnp[128 + i] = s2; bnp[192 + i] = b2[i] - m2[i] * s2;
    }
}

// ---- build per-tile CSR: entries (n_local | k<<8, m) ----
__global__ __launch_bounds__(256) void build_csr_kernel(const int* __restrict__ nbr,
                                                        int* __restrict__ tcnt,
                                                        int2* __restrict__ ents) {
    int n = blockIdx.x * 256 + threadIdx.x;
    if (n >= N_VOX) return;
    const int* row = nbr + (size_t)n * K27;
    const int tile = n >> 5, nl = n & 31;
#pragma unroll
    for (int k = 0; k < K27; ++k) {
        if (k == KC) continue;
        int m = row[k];
        if (m >= 0) {
            int slot = atomicAdd(&tcnt[tile], 1);
            if (slot < CAPT) ents[tile * CAPT + slot] = make_int2(nl | (k << 8), m);
        }
    }
}

// ---- fused layer kernel: one wave per 32-voxel tile ----
// L1: A from fp32 f (inline cvt), extras-a from fp32 f, out = bf16 midb
// L2: A from bf16 midb, extras-a from bf16 midb, out = fp32 d_out (+ residual f)
template <bool LAYER2>
__global__ __launch_bounds__(64) void fused_layer_kernel(const float* __restrict__ f,
                                                         const ushort* __restrict__ midb_in,
                                                         const ushort* __restrict__ pwc,  // this layer's frag slice
                                                         const ushort* __restrict__ pwv,  // this layer's VALU slice
                                                         const int* __restrict__ tcnt,
                                                         const int2* __restrict__ ents,
                                                         const float* __restrict__ bnp,   // s@0, h@64 (this layer)
                                                         ushort* __restrict__ midb_out,
                                                         float* __restrict__ fout) {
    __shared__ float ext[32 * C64];  // extras accumulator, 8 KB
    const int lane = threadIdx.x;
    const int tile = blockIdx.x;
    const int n0 = tile * 32;
    const int r16 = lane & 15, kg = lane >> 4;

    // zero extras tile
#pragma unroll
    for (int i = 0; i < 8; ++i) ((f32x4*)ext)[i * 64 + lane] = (f32x4)0.f;

    // ---- center: B fragments ----
    const short8* B = (const short8*)pwc;
    short8 Bf[2][4];
#pragma unroll
    for (int s = 0; s < 2; ++s)
#pragma unroll
        for (int t = 0; t < 4; ++t) Bf[s][t] = B[(s * 4 + t) * 64 + lane];

    f32x4 acc[2][4];
#pragma unroll
    for (int v = 0; v < 2; ++v)
#pragma unroll
        for (int t = 0; t < 4; ++t) acc[v][t] = (f32x4)0.f;

#pragma unroll
    for (int v = 0; v < 2; ++v) {
        short8 a0, a1;
        if (LAYER2) {
            const short8* ar = (const short8*)(midb_in + (size_t)(n0 + v * 16 + r16) * C64);
            a0 = ar[kg];
            a1 = ar[4 + kg];
        } else {
            const float4* ar = (const float4*)(f + (size_t)(n0 + v * 16 + r16) * C64);
            float4 fa = ar[kg * 2], fb = ar[kg * 2 + 1];
            float4 fc = ar[8 + kg * 2], fd = ar[9 + kg * 2];
            a0[0] = f2bf(fa.x); a0[1] = f2bf(fa.y); a0[2] = f2bf(fa.z); a0[3] = f2bf(fa.w);
            a0[4] = f2bf(fb.x); a0[5] = f2bf(fb.y); a0[6] = f2bf(fb.z); a0[7] = f2bf(fb.w);
            a1[0] = f2bf(fc.x); a1[1] = f2bf(fc.y); a1[2] = f2bf(fc.z); a1[3] = f2bf(fc.w);
            a1[4] = f2bf(fd.x); a1[5] = f2bf(fd.y); a1[6] = f2bf(fd.z); a1[7] = f2bf(fd.w);
        }
#pragma unroll
        for (int t = 0; t < 4; ++t) {
            acc[v][t] = __builtin_amdgcn_mfma_f32_16x16x32_bf16(a0, Bf[0][t], acc[v][t], 0, 0, 0);
            acc[v][t] = __builtin_amdgcn_mfma_f32_16x16x32_bf16(a1, Bf[1][t], acc[v][t], 0, 0, 0);
        }
    }

    // ---- extras: per pair, lane = output channel, accumulate into LDS ----
    int cnt = tcnt[tile];
    cnt = cnt > CAPT ? CAPT : cnt;
    for (int p = 0; p < cnt; ++p) {
        int2 e = ents[tile * CAPT + p];
        int nl = __builtin_amdgcn_readfirstlane(e.x & 255);
        int k  = __builtin_amdgcn_readfirstlane(e.x >> 8);
        int m  = __builtin_amdgcn_readfirstlane(e.y);
        const ushort* wk = pwv + (size_t)k * 4096 + lane;  // W[k][c][lane], stride 64
        float ee = 0.f;
        if (LAYER2) {
            const ushort* am = midb_in + (size_t)m * C64;
#pragma unroll
            for (int c = 0; c < C64; ++c)
                ee = fmaf(bf2f(am[c]), bf2f(wk[c * 64]), ee);
        } else {
            const float* am = f + (size_t)m * C64;
#pragma unroll
            for (int c = 0; c < C64; ++c)
                ee = fmaf(am[c], bf2f(wk[c * 64]), ee);
        }
        ext[nl * C64 + lane] += ee;
    }

    // ---- epilogue: BN (+resid) + ReLU, direct store ----
    float s[4], h[4];
#pragma unroll
    for (int t = 0; t < 4; ++t) {
        s[t] = bnp[t * 16 + r16];
        h[t] = bnp[64 + t * 16 + r16];
    }
#pragma unroll
    for (int v = 0; v < 2; ++v)
#pragma unroll
        for (int t = 0; t < 4; ++t)
#pragma unroll
            for (int r = 0; r < 4; ++r) {
                const int row = v * 16 + kg * 4 + r;
                const int ch = t * 16 + r16;
                float val = acc[v][t][r] + ext[row * C64 + ch];
                val = fmaf(val, s[t], h[t]);
                if (LAYER2) {
                    val += f[(size_t)(n0 + row) * C64 + ch];  // residual
                    fout[(size_t)(n0 + row) * C64 + ch] = fmaxf(val, 0.f);
                } else {
                    midb_out[(size_t)(n0 + row) * C64 + ch] = f2bf(fmaxf(val, 0.f));
                }
            }
}

extern "C" void kernel_launch(void* const* d_in, const int* in_sizes, int n_in,
                              void* d_out, int out_size, void* d_ws, size_t ws_size,
                              hipStream_t stream) {
    const float* f   = (const float*)d_in[0];
    const float* W1  = (const float*)d_in[1];
    const float* g1  = (const float*)d_in[2];
    const float* b1  = (const float*)d_in[3];
    const float* m1  = (const float*)d_in[4];
    const float* v1  = (const float*)d_in[5];
    const float* W2  = (const float*)d_in[6];
    const float* g2  = (const float*)d_in[7];
    const float* b2  = (const float*)d_in[8];
    const float* m2  = (const float*)d_in[9];
    const float* v2  = (const float*)d_in[10];
    const int*   nbr = (const int*)d_in[11];
    float* out = (float*)d_out;

    char* ws = (char*)d_ws;
    int*    tcnt = (int*)(ws + WS_TCNT);
    float*  bnp  = (float*)(ws + WS_BNP);
    ushort* pwc  = (ushort*)(ws + WS_PWC);
    ushort* pwv  = (ushort*)(ws + WS_PWV);
    int2*   ents = (int2*)(ws + WS_ENTS);
    ushort* midb = (ushort*)(ws + WS_MIDB);

    prep_kernel<<<911, 256, 0, stream>>>(W1, W2, g1, b1, m1, v1, g2, b2, m2, v2,
                                         pwv, pwc, tcnt, bnp);
    build_csr_kernel<<<(N_VOX + 255) / 256, 256, 0, stream>>>(nbr, tcnt, ents);

    fused_layer_kernel<false><<<TILES, 64, 0, stream>>>(
        f, nullptr, pwc, pwv, tcnt, ents, bnp, midb, nullptr);
    fused_layer_kernel<true><<<TILES, 64, 0, stream>>>(
        f, midb, pwc + 4096, pwv + LAYER_W, tcnt, ents, bnp + 128, nullptr, out);
}